// Round 7
// baseline (161.556 us; speedup 1.0000x reference)
//
#include <hip/hip_runtime.h>
#include <math.h>

// Amortized VI: per-row 3 MLPs (2->20->10->{4,4,6}), Cholesky reparam over
// P=8 samples, robot-arm FK likelihood, global mean.
//
// R6 insight: 2-row packing halved wave count (1024 blocks = 16 waves/CU,
// ~4/SIMD resident) -> latency (s_load K$, z loads) uncoverable; VALU 26%.
// Fix: 1 row/thread -> 2048 blocks, 32 waves/CU (8/SIMD) for TLP hiding,
// KEEP the register z-prefetch + sched_barrier pin from R6. VGPR target
// <=64 so full 8 waves/SIMD fit.
//
// Constants folded: C_PRIOR + C_LIK + C_ENT = 12.838199208
#define C_ALL 12.838199208f

struct WPtrs { const float* p[18]; };

__device__ __forceinline__ float softplus_f(float x) {
    return fmaxf(x, 0.0f) + __logf(1.0f + __expf(-fabsf(x)));
}

// MLP: y[2] @ W1[2][20] + b1 -> relu -> @ W2[20][10] + b2 -> relu -> @ W3[10][OD] + b3
// Weights wave-uniform -> s_load/SGPR operands. h1 fused into j-loop (1 live temp).
template <int OD>
__device__ __forceinline__ void mlp1(const float* __restrict__ W1,
                                     const float* __restrict__ b1,
                                     const float* __restrict__ W2,
                                     const float* __restrict__ b2,
                                     const float* __restrict__ W3,
                                     const float* __restrict__ b3,
                                     float y0, float y1, float* out) {
    float h2[10];
#pragma unroll
    for (int k = 0; k < 10; ++k) h2[k] = b2[k];
#pragma unroll
    for (int j = 0; j < 20; ++j) {
        const float h1 = fmaxf(0.0f, fmaf(y0, W1[j], fmaf(y1, W1[20 + j], b1[j])));
#pragma unroll
        for (int k = 0; k < 10; ++k) h2[k] = fmaf(h1, W2[j * 10 + k], h2[k]);
    }
#pragma unroll
    for (int k = 0; k < 10; ++k) h2[k] = fmaxf(0.0f, h2[k]);
#pragma unroll
    for (int d = 0; d < OD; ++d) out[d] = b3[d];
#pragma unroll
    for (int k = 0; k < 10; ++k) {
#pragma unroll
        for (int d = 0; d < OD; ++d) out[d] = fmaf(h2[k], W3[k * OD + d], out[d]);
    }
}

__global__ __launch_bounds__(256) void avi_kernel(
    const float* __restrict__ y, const float* __restrict__ zs, WPtrs wp,
    float* __restrict__ out, int N, float invN) {
    __shared__ float wsum[4];

    const int tid = threadIdx.x;
    const int n = blockIdx.x * 256 + tid;
    float rv = 0.0f;
    if (n < N) {
        const float2 yv = *reinterpret_cast<const float2*>(y + 2 * (size_t)n);
        const float y0 = yv.x, y1 = yv.y;

        // ---- prefetch: issue ALL 8 z loads before heavy compute ----
        const float4* zp = reinterpret_cast<const float4*>(zs + (size_t)n * 32);
        float4 z[8];
#pragma unroll
        for (int p = 0; p < 8; ++p) z[p] = zp[p];
        __builtin_amdgcn_sched_barrier(0);   // don't sink the loads past here

        float mu[4], ld[4], lo[6];
        mlp1<4>(wp.p[0], wp.p[1], wp.p[2], wp.p[3], wp.p[4], wp.p[5], y0, y1, mu);
        mlp1<4>(wp.p[6], wp.p[7], wp.p[8], wp.p[9], wp.p[10], wp.p[11], y0, y1, ld);
        mlp1<6>(wp.p[12], wp.p[13], wp.p[14], wp.p[15], wp.p[16], wp.p[17], y0, y1, lo);

        const float d0 = softplus_f(ld[0]);
        const float d1 = softplus_f(ld[1]);
        const float d2 = softplus_f(ld[2]);
        const float d3 = softplus_f(ld[3]);
        const float sumlogdiag = __logf(d0 * d1 * d2 * d3);
        const float L10 = lo[0], L20 = lo[1], L21 = lo[2];
        const float L30 = lo[3], L31 = lo[4], L32 = lo[5];

        float acc = 0.0f;
#pragma unroll
        for (int p = 0; p < 8; ++p) {
            const float xi0 = fmaf(d0, z[p].x, mu[0]);
            const float xi1 = fmaf(d1, z[p].y, fmaf(L10, z[p].x, mu[1]));
            const float xi2 = fmaf(d2, z[p].z, fmaf(L21, z[p].y, fmaf(L20, z[p].x, mu[2])));
            const float xi3 = fmaf(d3, z[p].w, fmaf(L32, z[p].z, fmaf(L31, z[p].y, fmaf(L30, z[p].x, mu[3]))));

            const float a1 = xi1, a2 = xi1 + xi2, a3 = a2 + xi3;
            float s1, c1, s2, c2, s3, c3;
            __sincosf(a1, &s1, &c1);
            __sincosf(a2, &s2, &c2);
            __sincosf(a3, &s3, &c3);
            const float px = fmaf(0.5f, c1, fmaf(0.5f, c2, c3));
            const float py = xi0 + fmaf(0.5f, s1, fmaf(0.5f, s2, s3));

            const float q0 = xi0 * 4.0f, q1 = xi1 * 2.0f, q2 = xi2 * 2.0f, q3 = xi3 * 2.0f;
            const float pq = fmaf(q0, q0, fmaf(q1, q1, fmaf(q2, q2, q3 * q3)));
            const float r0 = (y0 - px) * 100.0f;
            const float r1 = (y1 - py) * 100.0f;
            acc = fmaf(-0.5f, pq + fmaf(r0, r0, r1 * r1), acc);
        }
        rv = fmaf(0.125f, acc, C_ALL + sumlogdiag);
    }

    // wave (64) shuffle reduce, then cross-wave via LDS
#pragma unroll
    for (int d = 32; d > 0; d >>= 1) rv += __shfl_down(rv, d);
    if ((tid & 63) == 0) wsum[tid >> 6] = rv;
    __syncthreads();
    if (tid == 0) {
        const float s = wsum[0] + wsum[1] + wsum[2] + wsum[3];
        atomicAdd(out, s * invN);
    }
}

extern "C" void kernel_launch(void* const* d_in, const int* in_sizes, int n_in,
                              void* d_out, int out_size, void* d_ws, size_t ws_size,
                              hipStream_t stream) {
    const float* y = (const float*)d_in[0];
    const float* zs = (const float*)d_in[1];
    WPtrs wp;
    for (int i = 0; i < 18; ++i) wp.p[i] = (const float*)d_in[2 + i];
    float* out = (float*)d_out;
    const int N = in_sizes[0] / 2;

    hipMemsetAsync(out, 0, sizeof(float), stream);
    const int blocks = (N + 255) / 256;
    avi_kernel<<<blocks, 256, 0, stream>>>(y, zs, wp, out, N, 1.0f / (float)N);
}